// Round 1
// baseline (733.776 us; speedup 1.0000x reference)
//
#include <hip/hip_runtime.h>

// EBT transformer block on MI355X. All GEMMs via mfma_f32_16x16x32_bf16
// (fp32 accumulate), flash-style attention with swapped QK^T.

typedef __attribute__((ext_vector_type(8))) __bf16 bf16x8;
typedef __attribute__((ext_vector_type(8))) short short8;
typedef __attribute__((ext_vector_type(4))) float f32x4;

#define CDIM   768
#define HEADS  12
#define DH     64
#define SEQ    2048
#define BATCH  2
#define MROWS  4096      // B*S
#define QKV_N  2304      // 3*H*D
#define INTER  2048
#define GU_N   4096      // 2*INTER

static __device__ __forceinline__ unsigned short f2bf(float f) {
  unsigned int u = __builtin_bit_cast(unsigned int, f);
  u += 0x7fffu + ((u >> 16) & 1u);
  return (unsigned short)(u >> 16);
}

static __device__ __forceinline__ bf16x8 ld8(const unsigned short* p) {
  return __builtin_bit_cast(bf16x8, *reinterpret_cast<const short8*>(p));
}

// ---------------------------------------------------------------- casts ----
__global__ __launch_bounds__(256) void cast_all(
    const float* __restrict__ h, const float* __restrict__ wqkv,
    const float* __restrict__ wo, const float* __restrict__ wgu,
    const float* __restrict__ wd,
    unsigned short* __restrict__ hb, unsigned short* __restrict__ wqkvb,
    unsigned short* __restrict__ wob, unsigned short* __restrict__ wgub,
    unsigned short* __restrict__ wdb) {
  const int n0 = 3145728, n1 = 1769472, n2 = 589824, n3 = 3145728, n4 = 1572864;
  const int total = n0 + n1 + n2 + n3 + n4;
  for (int i = blockIdx.x * blockDim.x + threadIdx.x; i < total;
       i += gridDim.x * blockDim.x) {
    int j = i;
    if (j < n0) { hb[j]    = f2bf(h[j]);    continue; } j -= n0;
    if (j < n1) { wqkvb[j] = f2bf(wqkv[j]); continue; } j -= n1;
    if (j < n2) { wob[j]   = f2bf(wo[j]);   continue; } j -= n2;
    if (j < n3) { wgub[j]  = f2bf(wgu[j]);  continue; } j -= n3;
    wdb[j] = f2bf(wd[j]);
  }
}

// ----------------------------------------------------------------- GEMM ----
// C[m][n] = sum_k A[m][k] * W[n][k].  A: Mm x Kk row-major bf16,
// W: Nn x Kk row-major bf16, C fp32.  Block = 64x64 tile, 4 waves of 32x32.
__global__ __launch_bounds__(256) void gemm_bt(
    const unsigned short* __restrict__ A, const unsigned short* __restrict__ W,
    float* __restrict__ C, int Mm, int Nn, int Kk) {
  const int lane = threadIdx.x & 63;
  const int wid  = threadIdx.x >> 6;
  const int lr = lane & 15, lg = lane >> 4;
  const int row0 = blockIdx.y * 64 + (wid >> 1) * 32;
  const int col0 = blockIdx.x * 64 + (wid & 1) * 32;
  const unsigned short* Ap = A + (size_t)(row0 + lr) * Kk + lg * 8;
  const unsigned short* Wp = W + (size_t)(col0 + lr) * Kk + lg * 8;
  const size_t s16 = (size_t)16 * Kk;
  f32x4 acc00 = {0,0,0,0}, acc01 = {0,0,0,0}, acc10 = {0,0,0,0}, acc11 = {0,0,0,0};
  for (int k0 = 0; k0 < Kk; k0 += 32) {
    bf16x8 a0 = ld8(Ap + k0);
    bf16x8 a1 = ld8(Ap + s16 + k0);
    bf16x8 b0 = ld8(Wp + k0);
    bf16x8 b1 = ld8(Wp + s16 + k0);
    acc00 = __builtin_amdgcn_mfma_f32_16x16x32_bf16(a0, b0, acc00, 0, 0, 0);
    acc01 = __builtin_amdgcn_mfma_f32_16x16x32_bf16(a0, b1, acc01, 0, 0, 0);
    acc10 = __builtin_amdgcn_mfma_f32_16x16x32_bf16(a1, b0, acc10, 0, 0, 0);
    acc11 = __builtin_amdgcn_mfma_f32_16x16x32_bf16(a1, b1, acc11, 0, 0, 0);
  }
#pragma unroll
  for (int r = 0; r < 4; ++r) {
    C[(size_t)(row0 +      4*lg + r) * Nn + col0 +      lr] = acc00[r];
    C[(size_t)(row0 +      4*lg + r) * Nn + col0 + 16 + lr] = acc01[r];
    C[(size_t)(row0 + 16 + 4*lg + r) * Nn + col0 +      lr] = acc10[r];
    C[(size_t)(row0 + 16 + 4*lg + r) * Nn + col0 + 16 + lr] = acc11[r];
  }
}

// ----------------------------------------------------------------- RoPE ----
// qkv fp32 (B*S, 36*64) -> q,k bf16 (B,H,S,D) with rope, v bf16 (B,H,D,S).
__global__ __launch_bounds__(256) void rope_split(
    const float* __restrict__ qkv, const float* __restrict__ cosT,
    const float* __restrict__ sinT, unsigned short* __restrict__ qb,
    unsigned short* __restrict__ kbuf, unsigned short* __restrict__ vT) {
  const int row = blockIdx.x * 4 + (threadIdx.x >> 6);   // 0 .. B*S*36-1
  const int d = threadIdx.x & 63;
  const int hh = row % 36;
  const int bs = row / 36;
  const int s = bs & (SEQ - 1);
  const int b = bs >> 11;
  float v = qkv[(size_t)bs * QKV_N + hh * 64 + d];
  if (hh < 24) {
    float partner = __shfl_xor(v, 32, 64);
    float rot = (d < 32) ? -partner : partner;
    v = v * cosT[s * 64 + d] + rot * sinT[s * 64 + d];
  }
  unsigned short o = f2bf(v);
  if (hh < 12)
    qb[(((size_t)b * HEADS + hh) * SEQ + s) * DH + d] = o;
  else if (hh < 24)
    kbuf[(((size_t)b * HEADS + (hh - 12)) * SEQ + s) * DH + d] = o;
  else
    vT[(((size_t)b * HEADS + (hh - 24)) * DH + d) * SEQ + s] = o;
}

// ------------------------------------------------------------ attention ----
// One wave per 16 q-rows. Swapped QK^T: ST[key][q] = mfma(Kfrag, Qfrag).
// Online softmax per q-column, PV via ctx^T[d][q] = mfma(VTfrag, Pfrag).
__global__ __launch_bounds__(256) void attn_fused(
    const unsigned short* __restrict__ qb, const unsigned short* __restrict__ kbuf,
    const unsigned short* __restrict__ vT, unsigned short* __restrict__ ctx) {
  const int lane = threadIdx.x & 63, wid = threadIdx.x >> 6;
  const int tile = blockIdx.x * 4 + wid;      // 0 .. 3071
  const int qt = tile & 127, bh = tile >> 7;  // q-tile, batch*head
  const int lr = lane & 15, lg = lane >> 4;

  const unsigned short* qp = qb + ((size_t)bh * SEQ + qt * 16 + lr) * DH + lg * 8;
  bf16x8 qf0 = ld8(qp);
  bf16x8 qf1 = ld8(qp + 32);
  const unsigned short* kbase = kbuf + (size_t)bh * SEQ * DH + lg * 8;
  const unsigned short* vbase = vT + (size_t)bh * DH * SEQ + lg * 8;

  f32x4 acc0 = {0,0,0,0}, acc1 = {0,0,0,0}, acc2 = {0,0,0,0}, acc3 = {0,0,0,0};
  float m = -1e30f, l = 0.f;

  for (int k0 = 0; k0 < SEQ; k0 += 32) {
    const unsigned short* kp = kbase + (size_t)(k0 + lr) * DH;
    f32x4 st0 = {0,0,0,0}, st1 = {0,0,0,0};
    st0 = __builtin_amdgcn_mfma_f32_16x16x32_bf16(ld8(kp),           qf0, st0, 0,0,0);
    st0 = __builtin_amdgcn_mfma_f32_16x16x32_bf16(ld8(kp + 32),      qf1, st0, 0,0,0);
    st1 = __builtin_amdgcn_mfma_f32_16x16x32_bf16(ld8(kp + 16*DH),   qf0, st1, 0,0,0);
    st1 = __builtin_amdgcn_mfma_f32_16x16x32_bf16(ld8(kp + 16*DH+32),qf1, st1, 0,0,0);

    float tmax = -1e30f;
#pragma unroll
    for (int r = 0; r < 4; ++r) {
      st0[r] *= 0.125f; st1[r] *= 0.125f;
      tmax = fmaxf(tmax, fmaxf(st0[r], st1[r]));
    }
    tmax = fmaxf(tmax, __shfl_xor(tmax, 16, 64));
    tmax = fmaxf(tmax, __shfl_xor(tmax, 32, 64));
    float mn = fmaxf(m, tmax);
    float fac = __expf(m - mn);
    m = mn;
    l *= fac;
    acc0 *= fac; acc1 *= fac; acc2 *= fac; acc3 *= fac;

    float pa[4], pb[4], ls = 0.f;
#pragma unroll
    for (int r = 0; r < 4; ++r) {
      pa[r] = __expf(st0[r] - m);
      pb[r] = __expf(st1[r] - m);
      ls += pa[r] + pb[r];
    }
    ls += __shfl_xor(ls, 16, 64);
    ls += __shfl_xor(ls, 32, 64);
    l += ls;

    // Re-layout P^T (D-layout) into PV B-fragment via packed shuffles.
    unsigned int pk[4];
#pragma unroll
    for (int r = 0; r < 4; ++r)
      pk[r] = (unsigned)f2bf(pa[r]) | ((unsigned)f2bf(pb[r]) << 16);
    short8 pt;
    const int slb = (lg & 1) << 1;
#pragma unroll
    for (int i = 0; i < 8; ++i) {
      int sl = ((slb + (i >> 2)) << 4) + lr;
      unsigned w = (unsigned)__shfl((int)pk[i & 3], sl, 64);
      pt[i] = (short)((lg >= 2) ? (w >> 16) : (w & 0xffffu));
    }
    bf16x8 pf = __builtin_bit_cast(bf16x8, pt);

    acc0 = __builtin_amdgcn_mfma_f32_16x16x32_bf16(ld8(vbase + (size_t)(     lr) * SEQ + k0), pf, acc0, 0,0,0);
    acc1 = __builtin_amdgcn_mfma_f32_16x16x32_bf16(ld8(vbase + (size_t)(16 + lr) * SEQ + k0), pf, acc1, 0,0,0);
    acc2 = __builtin_amdgcn_mfma_f32_16x16x32_bf16(ld8(vbase + (size_t)(32 + lr) * SEQ + k0), pf, acc2, 0,0,0);
    acc3 = __builtin_amdgcn_mfma_f32_16x16x32_bf16(ld8(vbase + (size_t)(48 + lr) * SEQ + k0), pf, acc3, 0,0,0);
  }

  const float linv = 1.f / l;
  const int b = bh / HEADS, h = bh % HEADS;
  const int srow = qt * 16 + lr;
  unsigned short* cp = ctx + ((size_t)b * SEQ + srow) * CDIM + h * DH + 4 * lg;
#pragma unroll
  for (int r = 0; r < 4; ++r) {
    cp[r]      = f2bf(acc0[r] * linv);
    cp[16 + r] = f2bf(acc1[r] * linv);
    cp[32 + r] = f2bf(acc2[r] * linv);
    cp[48 + r] = f2bf(acc3[r] * linv);
  }
}

// ---------------------------------------------------------- add+rmsnorm ----
__global__ __launch_bounds__(256) void add_rmsnorm(
    const float* __restrict__ a, const float* __restrict__ b,
    float* __restrict__ outf, unsigned short* __restrict__ outb) {
  const int row = blockIdx.x;
  const int tid = threadIdx.x;
  const float* ap = a + (size_t)row * CDIM;
  const float* bp = b + (size_t)row * CDIM;
  float v0 = ap[tid]       + bp[tid];
  float v1 = ap[tid + 256] + bp[tid + 256];
  float v2 = ap[tid + 512] + bp[tid + 512];
  float ss = v0 * v0 + v1 * v1 + v2 * v2;
#pragma unroll
  for (int off = 32; off > 0; off >>= 1) ss += __shfl_xor(ss, off, 64);
  __shared__ float red[4];
  if ((tid & 63) == 0) red[tid >> 6] = ss;
  __syncthreads();
  float tot = red[0] + red[1] + red[2] + red[3];
  float r = rsqrtf(tot * (1.f / 768.f) + 1e-5f);
  float* of = outf + (size_t)row * CDIM;
  of[tid]       = v0 * r;
  of[tid + 256] = v1 * r;
  of[tid + 512] = v2 * r;
  if (outb) {
    unsigned short* ob = outb + (size_t)row * CDIM;
    ob[tid]       = f2bf(v0 * r);
    ob[tid + 256] = f2bf(v1 * r);
    ob[tid + 512] = f2bf(v2 * r);
  }
}

// ------------------------------------------------------------- silu*mul ----
__global__ __launch_bounds__(256) void silu_mul(
    const float* __restrict__ gu, unsigned short* __restrict__ hb) {
  const int i = blockIdx.x * 256 + threadIdx.x;  // < MROWS*INTER
  const int s = i >> 11, c = i & (INTER - 1);
  float g = gu[(size_t)s * GU_N + c];
  float u = gu[(size_t)s * GU_N + INTER + c];
  float sig = 1.f / (1.f + __expf(-g));
  hb[i] = f2bf(g * sig * u);
}

// ----------------------------------------------------------------- host ----
extern "C" void kernel_launch(void* const* d_in, const int* in_sizes, int n_in,
                              void* d_out, int out_size, void* d_ws, size_t ws_size,
                              hipStream_t stream) {
  const float* hidden = (const float*)d_in[0];
  const float* cosT   = (const float*)d_in[1];
  const float* sinT   = (const float*)d_in[2];
  const float* wqkv   = (const float*)d_in[3];
  const float* wo     = (const float*)d_in[4];
  const float* wgu    = (const float*)d_in[5];
  const float* wd     = (const float*)d_in[6];
  float* out = (float*)d_out;

  char* wsp = (char*)d_ws;
  size_t off = 0;
  auto alloc = [&](size_t bytes) { void* p = wsp + off; off += bytes; return p; };

  // persistent
  unsigned short* wqkvb = (unsigned short*)alloc(2ull * 1769472);
  unsigned short* wob   = (unsigned short*)alloc(2ull * 589824);
  unsigned short* wgub  = (unsigned short*)alloc(2ull * 3145728);
  unsigned short* wdb   = (unsigned short*)alloc(2ull * 1572864);
  unsigned short* hb    = (unsigned short*)alloc(2ull * 3145728);
  float*          x     = (float*)alloc(4ull * 3145728);
  unsigned short* xb    = (unsigned short*)alloc(2ull * 3145728);
  const size_t roff = off;

  // phase A (through attention)
  float*          qkv  = (float*)alloc(4ull * MROWS * QKV_N);
  unsigned short* qB   = (unsigned short*)alloc(2ull * MROWS * CDIM);
  unsigned short* kB   = (unsigned short*)alloc(2ull * MROWS * CDIM);
  unsigned short* vTb  = (unsigned short*)alloc(2ull * MROWS * CDIM);
  unsigned short* ctx  = (unsigned short*)alloc(2ull * MROWS * CDIM);
  float*          attn = (float*)alloc(4ull * MROWS * CDIM);

  // phase B (MLP) aliases phase A
  off = roff;
  float*          gu   = (float*)alloc(4ull * MROWS * GU_N);
  unsigned short* hmid = (unsigned short*)alloc(2ull * MROWS * INTER);
  float*          mlp  = (float*)alloc(4ull * MROWS * CDIM);
  (void)ws_size; (void)in_sizes; (void)n_in; (void)out_size;

  // 1. casts
  cast_all<<<4096, 256, 0, stream>>>(hidden, wqkv, wo, wgu, wd,
                                     hb, wqkvb, wob, wgub, wdb);
  // 2. qkv = hidden @ w_qkv^T
  gemm_bt<<<dim3(QKV_N / 64, MROWS / 64), 256, 0, stream>>>(
      hb, wqkvb, qkv, MROWS, QKV_N, CDIM);
  // 3. rope + split
  rope_split<<<(MROWS * 36) / 4, 256, 0, stream>>>(qkv, cosT, sinT, qB, kB, vTb);
  // 4. attention
  attn_fused<<<(BATCH * HEADS * (SEQ / 16)) / 4, 256, 0, stream>>>(qB, kB, vTb, ctx);
  // 5. attn_out = ctx @ w_o^T
  gemm_bt<<<dim3(CDIM / 64, MROWS / 64), 256, 0, stream>>>(
      ctx, wob, attn, MROWS, CDIM, CDIM);
  // 6. x = rmsnorm(hidden + attn)
  add_rmsnorm<<<MROWS, 256, 0, stream>>>(hidden, attn, x, xb);
  // 7. gu = x @ w_gate_up^T
  gemm_bt<<<dim3(GU_N / 64, MROWS / 64), 256, 0, stream>>>(
      xb, wgub, gu, MROWS, GU_N, CDIM);
  // 8. h = silu(gate)*up
  silu_mul<<<(MROWS * INTER) / 256, 256, 0, stream>>>(gu, hmid);
  // 9. mlp = h @ w_down^T
  gemm_bt<<<dim3(CDIM / 64, MROWS / 64), 256, 0, stream>>>(
      hmid, wdb, mlp, MROWS, CDIM, INTER);
  // 10. out = rmsnorm(x + mlp)
  add_rmsnorm<<<MROWS, 256, 0, stream>>>(x, mlp, out, nullptr);
}

// Round 3
// 454.273 us; speedup vs baseline: 1.6153x; 1.6153x over previous
//
#include <hip/hip_runtime.h>

// EBT transformer block on MI355X. All GEMMs via mfma_f32_16x16x32_bf16
// (fp32 accumulate) with global_load_lds staging (m97 structure);
// flash-style attention with swapped QK^T and permlane-based (LDS-free)
// softmax + P re-layout.

typedef __attribute__((ext_vector_type(8))) __bf16 bf16x8;
typedef __attribute__((ext_vector_type(8))) short short8;
typedef __attribute__((ext_vector_type(4))) short short4v;
typedef __attribute__((ext_vector_type(4))) float f32x4;
typedef __attribute__((ext_vector_type(4))) float float4v;
typedef __attribute__((ext_vector_type(4))) unsigned int u32x4;

#define CDIM   768
#define HEADS  12
#define DH     64
#define SEQ    2048
#define BATCH  2
#define MROWS  4096      // B*S
#define QKV_N  2304      // 3*H*D
#define INTER  2048
#define GU_N   4096      // 2*INTER

// log2(e)/8 folded into Q so scores are already in exp2 domain.
#define QSCALE 0.18033688011112043f

static __device__ __forceinline__ unsigned short f2bf(float f) {
  unsigned int u = __builtin_bit_cast(unsigned int, f);
  u += 0x7fffu + ((u >> 16) & 1u);
  return (unsigned short)(u >> 16);
}

static __device__ __forceinline__ bf16x8 ld8(const unsigned short* p) {
  return __builtin_bit_cast(bf16x8, *reinterpret_cast<const short8*>(p));
}

static __device__ __forceinline__ unsigned pack2bf(float lo, float hi) {
  unsigned short a = __builtin_bit_cast(unsigned short, (__bf16)lo);
  unsigned short b = __builtin_bit_cast(unsigned short, (__bf16)hi);
  return (unsigned)a | ((unsigned)b << 16);
}

// register-transpose building block: exchange reg-pair bit with lane bit5/bit4
static __device__ __forceinline__ void pl32swap(unsigned& a, unsigned& b) {
  auto r = __builtin_amdgcn_permlane32_swap(a, b, false, false);
  a = r[0]; b = r[1];
}
static __device__ __forceinline__ void pl16swap(unsigned& a, unsigned& b) {
  auto r = __builtin_amdgcn_permlane16_swap(a, b, false, false);
  a = r[0]; b = r[1];
}
// butterfly reduce across lane bit5 / bit4: one permlane + one op
static __device__ __forceinline__ float red32max(float x) {
  unsigned xi = __builtin_bit_cast(unsigned, x);
  auto r = __builtin_amdgcn_permlane32_swap(xi, xi, false, false);
  return fmaxf(__builtin_bit_cast(float, r[0]), __builtin_bit_cast(float, r[1]));
}
static __device__ __forceinline__ float red16max(float x) {
  unsigned xi = __builtin_bit_cast(unsigned, x);
  auto r = __builtin_amdgcn_permlane16_swap(xi, xi, false, false);
  return fmaxf(__builtin_bit_cast(float, r[0]), __builtin_bit_cast(float, r[1]));
}
static __device__ __forceinline__ float red32sum(float x) {
  unsigned xi = __builtin_bit_cast(unsigned, x);
  auto r = __builtin_amdgcn_permlane32_swap(xi, xi, false, false);
  return __builtin_bit_cast(float, r[0]) + __builtin_bit_cast(float, r[1]);
}
static __device__ __forceinline__ float red16sum(float x) {
  unsigned xi = __builtin_bit_cast(unsigned, x);
  auto r = __builtin_amdgcn_permlane16_swap(xi, xi, false, false);
  return __builtin_bit_cast(float, r[0]) + __builtin_bit_cast(float, r[1]);
}

// ---------------------------------------------------------------- casts ----
// all section sizes are %4==0, so vectorize float4 -> short4.
__global__ __launch_bounds__(256) void cast_all(
    const float* __restrict__ h, const float* __restrict__ wqkv,
    const float* __restrict__ wo, const float* __restrict__ wgu,
    const float* __restrict__ wd,
    unsigned short* __restrict__ hb, unsigned short* __restrict__ wqkvb,
    unsigned short* __restrict__ wob, unsigned short* __restrict__ wgub,
    unsigned short* __restrict__ wdb) {
  const int n0 = 786432, n1 = 442368, n2 = 147456, n3 = 786432, n4 = 393216;
  const int total = n0 + n1 + n2 + n3 + n4;   // in float4 units
  for (int i = blockIdx.x * blockDim.x + threadIdx.x; i < total;
       i += gridDim.x * blockDim.x) {
    int j = i;
    const float* src; unsigned short* dst;
    if      (j < n0)            { src = h;    dst = hb;    }
    else if ((j -= n0) < n1)    { src = wqkv; dst = wqkvb; }
    else if ((j -= n1) < n2)    { src = wo;   dst = wob;   }
    else if ((j -= n2) < n3)    { src = wgu;  dst = wgub;  }
    else    { j -= n3;            src = wd;   dst = wdb;   }
    float4v v = *reinterpret_cast<const float4v*>(src + 4 * (size_t)j);
    short4v o;
#pragma unroll
    for (int e = 0; e < 4; ++e) o[e] = (short)f2bf(v[e]);
    *reinterpret_cast<short4v*>(dst + 4 * (size_t)j) = o;
  }
}

// ----------------------------------------------------------------- GEMM ----
// C[m][n] = sum_k A[m][k] * W[n][k].  A: Mm x Kk bf16 row-major,
// W: Nn x Kk bf16 row-major, C fp32.  128x128 block tile, BK=32, 4 waves,
// global_load_lds staging (m97 structure). Mm,Nn %128==0, Kk %32==0.
__global__ __launch_bounds__(256) void gemm_lds(
    const unsigned short* __restrict__ A, const unsigned short* __restrict__ W,
    float* __restrict__ C, int Mm, int Nn, int Kk) {
  __shared__ unsigned short Alds[4096];   // [128][32]
  __shared__ unsigned short Blds[4096];   // [128][32]
  const int t = threadIdx.x;
  const int lane = t & 63, w = t >> 6;
  const int lr = lane & 15, lg = lane >> 4;
  const int row0 = blockIdx.y * 128, col0 = blockIdx.x * 128;
  const int wr = w >> 1, wc = w & 1;

  const unsigned short* ga = A + (size_t)(row0 + (t >> 2)) * Kk + (t & 3) * 8;
  const unsigned short* gb = W + (size_t)(col0 + (t >> 2)) * Kk + (t & 3) * 8;
  const size_t g64 = (size_t)64 * Kk;
  unsigned short* la0 = Alds + w * 512;   // wave-uniform LDS base
  unsigned short* lb0 = Blds + w * 512;
  const unsigned short* ra = Alds + (wr * 64 + lr) * 32 + lg * 8;
  const unsigned short* rb = Blds + (wc * 64 + lr) * 32 + lg * 8;

  f32x4 acc[4][4] = {};
  for (int k0 = 0; k0 < Kk; k0 += 32) {
    __builtin_amdgcn_global_load_lds((const unsigned int*)(ga + k0),
                                     (unsigned int*)la0, 16, 0, 0);
    __builtin_amdgcn_global_load_lds((const unsigned int*)(ga + k0 + g64),
                                     (unsigned int*)(la0 + 2048), 16, 0, 0);
    __builtin_amdgcn_global_load_lds((const unsigned int*)(gb + k0),
                                     (unsigned int*)lb0, 16, 0, 0);
    __builtin_amdgcn_global_load_lds((const unsigned int*)(gb + k0 + g64),
                                     (unsigned int*)(lb0 + 2048), 16, 0, 0);
    __syncthreads();
    bf16x8 af[4], bfr[4];
#pragma unroll
    for (int m = 0; m < 4; ++m) af[m] = ld8(ra + m * 512);
#pragma unroll
    for (int n = 0; n < 4; ++n) bfr[n] = ld8(rb + n * 512);
#pragma unroll
    for (int m = 0; m < 4; ++m)
#pragma unroll
      for (int n = 0; n < 4; ++n)
        acc[m][n] = __builtin_amdgcn_mfma_f32_16x16x32_bf16(af[m], bfr[n],
                                                            acc[m][n], 0, 0, 0);
    __syncthreads();
  }
#pragma unroll
  for (int m = 0; m < 4; ++m)
#pragma unroll
    for (int j = 0; j < 4; ++j) {
      float* cr = C + (size_t)(row0 + wr * 64 + m * 16 + lg * 4 + j) * Nn +
                  col0 + wc * 64 + lr;
#pragma unroll
      for (int n = 0; n < 4; ++n) cr[n * 16] = acc[m][n][j];
    }
}

// ----------------------------------------------------------------- RoPE ----
// q,k rows of qkv fp32 -> q bf16 (scaled by QSCALE), k bf16, (B,H,S,D).
__global__ __launch_bounds__(256) void rope_qk(
    const float* __restrict__ qkv, const float* __restrict__ cosT,
    const float* __restrict__ sinT, unsigned short* __restrict__ qb,
    unsigned short* __restrict__ kbuf) {
  const int row = blockIdx.x * 4 + (threadIdx.x >> 6);   // 0 .. B*S*24-1
  const int d = threadIdx.x & 63;
  const int hh = row % 24;
  const int bs = row / 24;
  const int s = bs & (SEQ - 1);
  const int b = bs >> 11;
  float v = qkv[(size_t)bs * QKV_N + hh * 64 + d];
  float partner = __shfl_xor(v, 32, 64);
  float rot = (d < 32) ? -partner : partner;
  v = v * cosT[s * 64 + d] + rot * sinT[s * 64 + d];
  if (hh < 12)
    qb[(((size_t)b * HEADS + hh) * SEQ + s) * DH + d] = f2bf(v * QSCALE);
  else
    kbuf[(((size_t)b * HEADS + (hh - 12)) * SEQ + s) * DH + d] = f2bf(v);
}

// V transpose through padded LDS: qkv fp32 (B*S, ...) -> v bf16 (B,H,D,S).
__global__ __launch_bounds__(256) void v_trans(
    const float* __restrict__ qkv, unsigned short* __restrict__ vT) {
  __shared__ float tile[64][65];
  const int bh = blockIdx.x;               // b*HEADS+h
  const int s0 = blockIdx.y * 64;
  const int b = bh / HEADS, h = bh % HEADS;
  const float* src = qkv + ((size_t)(b * SEQ + s0)) * QKV_N + (24 + h) * 64;
  const int d = threadIdx.x & 63, sg = threadIdx.x >> 6;
#pragma unroll
  for (int i = 0; i < 16; ++i) {
    int s = sg * 16 + i;
    tile[s][d] = src[(size_t)s * QKV_N + d];
  }
  __syncthreads();
  unsigned short* dst = vT + (size_t)bh * DH * SEQ + s0;
  const int sl = threadIdx.x & 63, dg = threadIdx.x >> 6;
#pragma unroll
  for (int i = 0; i < 16; ++i) {
    int dd = dg * 16 + i;
    dst[(size_t)dd * SEQ + sl] = f2bf(tile[sl][dd]);
  }
}

// ------------------------------------------------------------ attention ----
// One wave per 16 q-rows. Swapped QK^T: ST[key][q] = mfma(Kfrag, Qfrag).
// Scores arrive pre-scaled by log2(e)/8 (folded into Q). Online softmax in
// exp2 domain with defer-max; P re-layout via permlane register transpose.
__global__ __launch_bounds__(256) void attn_fused(
    const unsigned short* __restrict__ qb, const unsigned short* __restrict__ kbuf,
    const unsigned short* __restrict__ vT, unsigned short* __restrict__ ctx) {
  const int lane = threadIdx.x & 63, wid = threadIdx.x >> 6;
  const int tile = blockIdx.x * 4 + wid;      // 0 .. 3071
  const int qt = tile & 127, bh = tile >> 7;  // q-tile, batch*head
  const int lr = lane & 15, lg = lane >> 4;

  const unsigned short* qp = qb + ((size_t)bh * SEQ + qt * 16 + lr) * DH + lg * 8;
  bf16x8 qf0 = ld8(qp);
  bf16x8 qf1 = ld8(qp + 32);
  const unsigned short* kbase = kbuf + (size_t)bh * SEQ * DH + lg * 8;
  const unsigned short* vbase = vT + (size_t)bh * DH * SEQ + lg * 8;

  f32x4 acc0 = {0,0,0,0}, acc1 = {0,0,0,0}, acc2 = {0,0,0,0}, acc3 = {0,0,0,0};
  float m = -1e30f, l = 0.f;

  for (int k0 = 0; k0 < SEQ; k0 += 32) {
    const unsigned short* kp = kbase + (size_t)(k0 + lr) * DH;
    f32x4 st0 = {0,0,0,0}, st1 = {0,0,0,0};
    st0 = __builtin_amdgcn_mfma_f32_16x16x32_bf16(ld8(kp),           qf0, st0, 0,0,0);
    st0 = __builtin_amdgcn_mfma_f32_16x16x32_bf16(ld8(kp + 32),      qf1, st0, 0,0,0);
    st1 = __builtin_amdgcn_mfma_f32_16x16x32_bf16(ld8(kp + 16*DH),   qf0, st1, 0,0,0);
    st1 = __builtin_amdgcn_mfma_f32_16x16x32_bf16(ld8(kp + 16*DH+32),qf1, st1, 0,0,0);

    // per-q-column max over 32 keys: 7 fmax + 2 permlane butterflies
    float tmax = fmaxf(fmaxf(fmaxf(st0[0], st0[1]), fmaxf(st0[2], st0[3])),
                       fmaxf(fmaxf(st1[0], st1[1]), fmaxf(st1[2], st1[3])));
    tmax = red16max(red32max(tmax));

    if (tmax > m + 11.0f) {   // defer-max: rescale only on real growth
      float fac = exp2f(m - tmax);
      m = tmax;
      l *= fac;
      acc0 *= fac; acc1 *= fac; acc2 *= fac; acc3 *= fac;
    }

    float pa[4], pb[4];
#pragma unroll
    for (int r = 0; r < 4; ++r) {
      pa[r] = exp2f(st0[r] - m);
      pb[r] = exp2f(st1[r] - m);
    }
    float ls = ((pa[0] + pa[1]) + (pa[2] + pa[3])) +
               ((pb[0] + pb[1]) + (pb[2] + pb[3]));
    l += red16sum(red32sum(ls));

    // Register transpose: key bits (k4 | k3 k2 = lanegrp | k1 k0 = reg) ->
    // B-fragment (lanegrp = k4 k3, dword = k2 k1, half = k0).
    unsigned c0 = pack2bf(pa[0], pa[1]);
    unsigned c1 = pack2bf(pa[2], pa[3]);
    unsigned c2 = pack2bf(pb[0], pb[1]);
    unsigned c3 = pack2bf(pb[2], pb[3]);
    pl32swap(c0, c2);  // reg-pair bit <-> lane bit5
    pl32swap(c1, c3);
    pl16swap(c0, c2);  // reg-pair bit <-> lane bit4
    pl16swap(c1, c3);
    u32x4 pw = {c0, c1, c2, c3};           // lane lg holds keys 8lg..8lg+7
    bf16x8 pf = __builtin_bit_cast(bf16x8, pw);

    acc0 = __builtin_amdgcn_mfma_f32_16x16x32_bf16(ld8(vbase + (size_t)(     lr) * SEQ + k0), pf, acc0, 0,0,0);
    acc1 = __builtin_amdgcn_mfma_f32_16x16x32_bf16(ld8(vbase + (size_t)(16 + lr) * SEQ + k0), pf, acc1, 0,0,0);
    acc2 = __builtin_amdgcn_mfma_f32_16x16x32_bf16(ld8(vbase + (size_t)(32 + lr) * SEQ + k0), pf, acc2, 0,0,0);
    acc3 = __builtin_amdgcn_mfma_f32_16x16x32_bf16(ld8(vbase + (size_t)(48 + lr) * SEQ + k0), pf, acc3, 0,0,0);
  }

  const float linv = 1.f / l;
  const int b = bh / HEADS, h = bh % HEADS;
  unsigned short* cp = ctx + ((size_t)b * SEQ + qt * 16 + lr) * CDIM + h * DH + 4 * lg;
  short4v o0, o1, o2, o3;
#pragma unroll
  for (int r = 0; r < 4; ++r) {
    o0[r] = (short)f2bf(acc0[r] * linv);
    o1[r] = (short)f2bf(acc1[r] * linv);
    o2[r] = (short)f2bf(acc2[r] * linv);
    o3[r] = (short)f2bf(acc3[r] * linv);
  }
  *reinterpret_cast<short4v*>(cp)      = o0;
  *reinterpret_cast<short4v*>(cp + 16) = o1;
  *reinterpret_cast<short4v*>(cp + 32) = o2;
  *reinterpret_cast<short4v*>(cp + 48) = o3;
}

// ---------------------------------------------------------- add+rmsnorm ----
__global__ __launch_bounds__(256) void add_rmsnorm(
    const float* __restrict__ a, const float* __restrict__ b,
    float* __restrict__ outf, unsigned short* __restrict__ outb) {
  const int row = blockIdx.x;
  const int tid = threadIdx.x;
  const float* ap = a + (size_t)row * CDIM;
  const float* bp = b + (size_t)row * CDIM;
  float v0 = ap[tid]       + bp[tid];
  float v1 = ap[tid + 256] + bp[tid + 256];
  float v2 = ap[tid + 512] + bp[tid + 512];
  float ss = v0 * v0 + v1 * v1 + v2 * v2;
#pragma unroll
  for (int off = 32; off > 0; off >>= 1) ss += __shfl_xor(ss, off, 64);
  __shared__ float red[4];
  if ((tid & 63) == 0) red[tid >> 6] = ss;
  __syncthreads();
  float tot = red[0] + red[1] + red[2] + red[3];
  float r = rsqrtf(tot * (1.f / 768.f) + 1e-5f);
  float* of = outf + (size_t)row * CDIM;
  of[tid]       = v0 * r;
  of[tid + 256] = v1 * r;
  of[tid + 512] = v2 * r;
  if (outb) {
    unsigned short* ob = outb + (size_t)row * CDIM;
    ob[tid]       = f2bf(v0 * r);
    ob[tid + 256] = f2bf(v1 * r);
    ob[tid + 512] = f2bf(v2 * r);
  }
}

// ------------------------------------------------------------- silu*mul ----
__global__ __launch_bounds__(256) void silu_mul(
    const float* __restrict__ gu, unsigned short* __restrict__ hb) {
  const int i = blockIdx.x * 256 + threadIdx.x;  // < MROWS*INTER
  const int s = i >> 11, c = i & (INTER - 1);
  float g = gu[(size_t)s * GU_N + c];
  float u = gu[(size_t)s * GU_N + INTER + c];
  float sig = 1.f / (1.f + __expf(-g));
  hb[i] = f2bf(g * sig * u);
}

// ----------------------------------------------------------------- host ----
extern "C" void kernel_launch(void* const* d_in, const int* in_sizes, int n_in,
                              void* d_out, int out_size, void* d_ws, size_t ws_size,
                              hipStream_t stream) {
  const float* hidden = (const float*)d_in[0];
  const float* cosT   = (const float*)d_in[1];
  const float* sinT   = (const float*)d_in[2];
  const float* wqkv   = (const float*)d_in[3];
  const float* wo     = (const float*)d_in[4];
  const float* wgu    = (const float*)d_in[5];
  const float* wd     = (const float*)d_in[6];
  float* out = (float*)d_out;

  char* wsp = (char*)d_ws;
  size_t off = 0;
  auto alloc = [&](size_t bytes) { void* p = wsp + off; off += bytes; return p; };

  // persistent
  unsigned short* wqkvb = (unsigned short*)alloc(2ull * 1769472);
  unsigned short* wob   = (unsigned short*)alloc(2ull * 589824);
  unsigned short* wgub  = (unsigned short*)alloc(2ull * 3145728);
  unsigned short* wdb   = (unsigned short*)alloc(2ull * 1572864);
  unsigned short* hb    = (unsigned short*)alloc(2ull * 3145728);
  float*          x     = (float*)alloc(4ull * 3145728);
  unsigned short* xb    = (unsigned short*)alloc(2ull * 3145728);
  const size_t roff = off;

  // phase A (through attention)
  float*          qkv  = (float*)alloc(4ull * MROWS * QKV_N);
  unsigned short* qB   = (unsigned short*)alloc(2ull * MROWS * CDIM);
  unsigned short* kB   = (unsigned short*)alloc(2ull * MROWS * CDIM);
  unsigned short* vTb  = (unsigned short*)alloc(2ull * MROWS * CDIM);
  unsigned short* ctx  = (unsigned short*)alloc(2ull * MROWS * CDIM);
  float*          attn = (float*)alloc(4ull * MROWS * CDIM);

  // phase B (MLP) aliases phase A
  off = roff;
  float*          gu   = (float*)alloc(4ull * MROWS * GU_N);
  unsigned short* hmid = (unsigned short*)alloc(2ull * MROWS * INTER);
  float*          mlp  = (float*)alloc(4ull * MROWS * CDIM);
  (void)ws_size; (void)in_sizes; (void)n_in; (void)out_size;

  // 1. casts
  cast_all<<<2048, 256, 0, stream>>>(hidden, wqkv, wo, wgu, wd,
                                     hb, wqkvb, wob, wgub, wdb);
  // 2. qkv = hidden @ w_qkv^T
  gemm_lds<<<dim3(QKV_N / 128, MROWS / 128), 256, 0, stream>>>(
      hb, wqkvb, qkv, MROWS, QKV_N, CDIM);
  // 3. rope (q,k) + v transpose
  rope_qk<<<(MROWS * 24) / 4, 256, 0, stream>>>(qkv, cosT, sinT, qB, kB);
  v_trans<<<dim3(BATCH * HEADS, SEQ / 64), 256, 0, stream>>>(qkv, vTb);
  // 4. attention
  attn_fused<<<(BATCH * HEADS * (SEQ / 16)) / 4, 256, 0, stream>>>(qB, kB, vTb, ctx);
  // 5. attn_out = ctx @ w_o^T
  gemm_lds<<<dim3(CDIM / 128, MROWS / 128), 256, 0, stream>>>(
      ctx, wob, attn, MROWS, CDIM, CDIM);
  // 6. x = rmsnorm(hidden + attn)
  add_rmsnorm<<<MROWS, 256, 0, stream>>>(hidden, attn, x, xb);
  // 7. gu = x @ w_gate_up^T
  gemm_lds<<<dim3(GU_N / 128, MROWS / 128), 256, 0, stream>>>(
      xb, wgub, gu, MROWS, GU_N, CDIM);
  // 8. h = silu(gate)*up
  silu_mul<<<(MROWS * INTER) / 256, 256, 0, stream>>>(gu, hmid);
  // 9. mlp = h @ w_down^T
  gemm_lds<<<dim3(CDIM / 128, MROWS / 128), 256, 0, stream>>>(
      hmid, wdb, mlp, MROWS, CDIM, INTER);
  // 10. out = rmsnorm(x + mlp)
  add_rmsnorm<<<MROWS, 256, 0, stream>>>(x, mlp, out, nullptr);
}